// Round 10
// baseline (242.839 us; speedup 1.0000x reference)
//
#include <hip/hip_runtime.h>

// Problem constants
#define S_LEN 2048
#define NH    16
#define HD    64
#define EMB   1024
#define NB    4
#define MROWS (NB * S_LEN)   // 8192

typedef __attribute__((ext_vector_type(8))) short  short8;   // 8 x bf16 bits (4 VGPRs)
typedef __attribute__((ext_vector_type(4))) float  float4_t; // MFMA C/D frag
typedef __attribute__((ext_vector_type(4))) int    int4_t;   // 16B int vector
union U8 { int4_t i; short8 s; };

__device__ __forceinline__ unsigned short f2bf(float f) {
    unsigned int x = __float_as_uint(f);
    unsigned int r = (x + 0x7fffu + ((x >> 16) & 1u)) >> 16;   // RNE
    return (unsigned short)r;
}

__device__ __forceinline__ unsigned int cvtpk_bf16(float lo, float hi) {
    unsigned int r;
    asm("v_cvt_pk_bf16_f32 %0, %1, %2" : "=v"(r) : "v"(lo), "v"(hi));
    return r;   // lo16 = bf16(lo), hi16 = bf16(hi), RNE
}

typedef const __attribute__((address_space(1))) unsigned int* gas_ptr;
typedef __attribute__((address_space(3))) unsigned int*       las_ptr;
__device__ __forceinline__ void gld_lds16(const void* g, void* l) {
    __builtin_amdgcn_global_load_lds((gas_ptr)g, (las_ptr)l, 16, 0, 0);
}

template<bool B> struct BoolC { static constexpr bool v = B; };

// Q pre-scale: 0.125 (1/sqrt(HD)) * log2(e) -> scores emerge in log2 domain
#define QSCALE 0.18033688011112042f

// ---------------------------------------------------------------------------
// prep: fused  (a) x f32->bf16 cvt, (b) Wqkv transpose, (c) Wout transpose.
// ---------------------------------------------------------------------------
__global__ __launch_bounds__(256) void prep(
    const float* __restrict__ x,    unsigned short* __restrict__ Xb,
    const float* __restrict__ Wqkv, unsigned short* __restrict__ WqkvT,
    const float* __restrict__ Wout, unsigned short* __restrict__ WoutT)
{
    __shared__ float tile[32][33];
    int bid = blockIdx.x, t = threadIdx.x;
    if (bid < 16384) {                       // cvt: 16384*256 = MROWS*EMB/2 exact
        int i = bid * 256 + t;
        float2 v = ((const float2*)x)[i];
        ushort2 o; o.x = f2bf(v.x); o.y = f2bf(v.y);
        ((ushort2*)Xb)[i] = o;
        return;
    }
    const float* in; unsigned short* out; int R, C, n0, r0;
    if (bid < 19456) {                       // Wqkv transpose: 96 x 32 tiles
        int b2 = bid - 16384;
        in = Wqkv; out = WqkvT; R = EMB; C = 3 * EMB;
        n0 = (b2 % 96) * 32; r0 = (b2 / 96) * 32;
    } else {                                 // Wout transpose: 32 x 32 tiles
        int b2 = bid - 19456;
        in = Wout; out = WoutT; R = EMB; C = EMB;
        n0 = (b2 & 31) * 32; r0 = (b2 >> 5) * 32;
    }
    int tx = t & 31, ty = t >> 5;
#pragma unroll
    for (int i = 0; i < 4; ++i)
        tile[ty + i * 8][tx] = in[(size_t)(r0 + ty + i * 8) * C + n0 + tx];
    __syncthreads();
#pragma unroll
    for (int i = 0; i < 4; ++i)
        out[(size_t)(n0 + ty + i * 8) * R + r0 + tx] = f2bf(tile[tx][ty + i * 8]);
}

// ---------------------------------------------------------------------------
// GEMM1: qkv = Xb[8192,1024] @ WqkvT[3072,1024]^T + bqkv(f32)
// ROUND 10: __launch_bounds__(256, 3).  R9 counters: VGPR_Count=68 while
// the (256,2) cap is 128 -- the binding constraint on occupancy (26% = 2
// blocks/CU) is the BOUND, not the usage.  (256,3) cap = 85 >= 68 (no-spill
// headroom, R5 lesson checked) -> 3 waves/SIMD -> 3 blocks/CU (LDS 3x48KB
// = 144KB <= 160KB).  +50% TLP to overlap the per-tile vmcnt/barrier waits
// that cap MfmaUtil at 32%.  Everything else unchanged from R9 (fixed
// (row>>1)&3 swizzle: conflicts 6.29M->393K; coalesced LDS-staged epilogue:
// WRITE 64->49MB; counted-vmcnt 3-slot pipeline).
// ---------------------------------------------------------------------------
__global__ __launch_bounds__(256, 3) void gemm_qkv(
    const unsigned short* __restrict__ X,
    const unsigned short* __restrict__ WT,
    const float* __restrict__ bias,
    unsigned short* __restrict__ Qb,
    unsigned short* __restrict__ Kb,
    unsigned short* __restrict__ VTb)
{
    // 48KB: A slots [0,12288), B slots [12288,24576); epilogue staging
    // reuses [0, 16896) after a full __syncthreads.
    __shared__ alignas(16) unsigned short smem[24576];
    const int K = 1024;
    const int NT = K / 32;                 // 32 K-tiles
    int t = threadIdx.x;
    int wave = t >> 6, lane = t & 63, quad = lane >> 4, l = lane & 15;
    int bm = blockIdx.x * 128, bn = blockIdx.y * 128;
    int wm = (wave >> 1) * 64, wn = (wave & 1) * 64;
    int colrd = (quad ^ ((l >> 1) & 3)) * 8;   // swizzle read slot

    float4_t z = {0.f, 0.f, 0.f, 0.f};
    float4_t acc[4][4];
#pragma unroll
    for (int i = 0; i < 4; ++i)
#pragma unroll
        for (int j = 0; j < 4; ++j) acc[i][j] = z;

    auto stage = [&](int kt, int slot) {
        int k0 = kt * 32;
        unsigned short* Ad = smem + slot * 4096;
        unsigned short* Bd = smem + 12288 + slot * 4096;
#pragma unroll
        for (int it = 0; it < 2; ++it) {
            int c = t + 256 * it;
            int row = c >> 2;
            int col = ((c & 3) ^ ((c >> 3) & 3)) * 8;   // (c>>3)&3 == (row>>1)&3
            gld_lds16(&X [(size_t)(bm + row) * K + k0 + col], &Ad[c * 8]);
            gld_lds16(&WT[(size_t)(bn + row) * K + k0 + col], &Bd[c * 8]);
        }
    };

    auto compute = [&](int slot) {
        const unsigned short* Ac = smem + slot * 4096;
        const unsigned short* Bc = smem + 12288 + slot * 4096;
        short8 af[4], bfr[4];
#pragma unroll
        for (int i = 0; i < 4; ++i)
            af[i] = *(const short8*)&Ac[(wm + i * 16 + l) * 32 + colrd];
#pragma unroll
        for (int j = 0; j < 4; ++j)
            bfr[j] = *(const short8*)&Bc[(wn + j * 16 + l) * 32 + colrd];
#pragma unroll
        for (int i = 0; i < 4; ++i)
#pragma unroll
            for (int j = 0; j < 4; ++j)
                acc[i][j] = __builtin_amdgcn_mfma_f32_16x16x32_bf16(
                    af[i], bfr[j], acc[i][j], 0, 0, 0);
    };

    stage(0, 0);
    stage(1, 1);
    int cs = 0, ss = 2;
    for (int u = 0; u < NT; ++u) {
        if (u + 1 < NT) {
            asm volatile("s_waitcnt vmcnt(4)" ::: "memory");  // own tile-u loads done
        } else {
            asm volatile("s_waitcnt vmcnt(0)" ::: "memory");
        }
        __builtin_amdgcn_s_barrier();
        __builtin_amdgcn_sched_barrier(0);
        if (u + 2 < NT) stage(u + 2, ss);
        compute(cs);
        cs = (cs == 2) ? 0 : cs + 1;
        ss = (ss == 2) ? 0 : ss + 1;
    }

    // ---- LDS-staged coalesced epilogue ----
    __syncthreads();                       // all waves done reading K-loop LDS
    int which = bn >> 10;                  // block-uniform (bn mult of 128)
    int bnr = bn & 1023;
    int b = bm >> 11;
    if (which == 2) {
        // V: stage transposed [c][pi-slot(s)] (stride 132 shorts)
#pragma unroll
        for (int j = 0; j < 4; ++j) {
            float bv = bias[bn + wn + j * 16 + l];
            int c = wn + j * 16 + l;
#pragma unroll
            for (int i = 0; i < 4; ++i) {
                uint2 vv;
                vv.x = cvtpk_bf16(acc[i][j][0] + bv, acc[i][j][1] + bv);
                vv.y = cvtpk_bf16(acc[i][j][2] + bv, acc[i][j][3] + bv);
                // pi([i|quad|r]) = quad*16 + i*4 + r, within the wm 64-group
                *(uint2*)&smem[c * 132 + wm + quad * 16 + i * 4] = vv;
            }
        }
        __syncthreads();
        int sbase = bm & 2047;
#pragma unroll
        for (int pass = 0; pass < 8; ++pass) {
            int c = pass * 16 + (t >> 4);
            int sp = (t & 15) * 8;
            int rem = bnr + c, h = rem >> 6, d = rem & 63;
            uint2 lo = *(const uint2*)&smem[c * 132 + sp];
            uint2 hi = *(const uint2*)&smem[c * 132 + sp + 4];
            int4_t v = {(int)lo.x, (int)lo.y, (int)hi.x, (int)hi.y};
            *(int4_t*)&VTb[((size_t)(b * NH + h) * HD + d) * S_LEN + sbase + sp] = v;
        }
    } else {
        // Q/K: stage [s][c] (stride 132 shorts)
#pragma unroll
        for (int j = 0; j < 4; ++j) {
            float bv = bias[bn + wn + j * 16 + l];
            int c = wn + j * 16 + l;
#pragma unroll
            for (int i = 0; i < 4; ++i)
#pragma unroll
                for (int r = 0; r < 4; ++r) {
                    float ov = acc[i][j][r] + bv;
                    if (which == 0) ov *= QSCALE;
                    smem[(wm + i * 16 + quad * 4 + r) * 132 + c] = f2bf(ov);
                }
        }
        __syncthreads();
        unsigned short* dst = which ? Kb : Qb;
        int s0g = bm & 2047;
#pragma unroll
        for (int pass = 0; pass < 8; ++pass) {
            int s = pass * 16 + (t >> 4);
            int cp = (t & 15) * 8;
            int rem = bnr + cp, h = rem >> 6, d = rem & 63;
            uint2 lo = *(const uint2*)&smem[s * 132 + cp];
            uint2 hi = *(const uint2*)&smem[s * 132 + cp + 4];
            int4_t v = {(int)lo.x, (int)lo.y, (int)hi.x, (int)hi.y};
            *(int4_t*)&dst[((size_t)(b * NH + h) * S_LEN + s0g + s) * HD + d] = v;
        }
    }
}

// ---------------------------------------------------------------------------
// Flash attention (causal), LDS-staged K/V shared across the block.
// (Unchanged: counted-vmcnt 3-slot pipeline, balanced chunks, permuted-V
// single-b128 PV reads, MFMA row-sum denominator.  Stays (256,2): measured
// VGPR_Count=88 > the 85 cap a (256,3) bound would impose -> would spill.)
// ---------------------------------------------------------------------------
__global__ __launch_bounds__(256, 2) void flash_attn(
    const unsigned short* __restrict__ Qb,
    const unsigned short* __restrict__ Kb,
    const unsigned short* __restrict__ VTb,
    unsigned short* __restrict__ AO)
{
    // 3 buffers x (K 8KB | V 8KB) = 48KB; epilogue reuses first 8704B as
    // per-wave O staging (after full __syncthreads).
    __shared__ alignas(16) unsigned short smem[24576];

    int t = threadIdx.x, wave = t >> 6, lane = t & 63, quad = lane >> 4, cl = lane & 15;
    int blk = blockIdx.x;                        // 0..1023
    int bh = (blk & 7) + 8 * ((blk >> 3) & 7);   // XCD-pinned heads
    int g = blk >> 6;                            // 0..15
    int b = bh >> 4, h = bh & 15;
    int ci = (wave & 2) ? (62 - 2 * g + (wave & 1)) : (2 * g + (wave & 1));
    int qb = 32 * ci;
    int nkt = (ci >> 1) + 1;                     // tiles this wave computes
    int nkt_max = 32 - g;                        // tiles the block stages (>=17)

    const unsigned short* Qbase = Qb  + (size_t)bh * S_LEN * HD;
    const unsigned short* Kbase = Kb  + (size_t)bh * S_LEN * HD;
    const unsigned short* Vbase = VTb + (size_t)bh * HD * S_LEN;

    float4_t z = {0.f, 0.f, 0.f, 0.f};
    short8 onesf;
#pragma unroll
    for (int i = 0; i < 8; ++i) onesf[i] = (short)0x3F80;   // bf16 1.0

    short8 bQ[2][2];
#pragma unroll
    for (int qt = 0; qt < 2; ++qt)
#pragma unroll
        for (int hh = 0; hh < 2; ++hh)
            bQ[qt][hh] = *(const short8*)&Qbase[(size_t)(qb + qt * 16 + cl) * HD + hh * 32 + quad * 8];

    float4_t acc[2][4], accs[2];
#pragma unroll
    for (int qt = 0; qt < 2; ++qt) {
        accs[qt] = z;
#pragma unroll
        for (int nb = 0; nb < 4; ++nb) acc[qt][nb] = z;
    }

    // kt-invariant swizzled LDS read offsets (bytes, relative to buffer base)
    int koff0[4], koff1[4];
#pragma unroll
    for (int t4 = 0; t4 < 4; ++t4) {
        int row = t4 * 16 + cl, sw = row & 7;
        koff0[t4] = (row << 7) | ((quad ^ sw) << 4);
        koff1[t4] = (row << 7) | (((quad + 4) ^ sw) << 4);
    }
    // V (permuted layout): B-frag for (p,quad) at 16B slot (quad*2+p)^(row&7)
    int voffB[2][4];
#pragma unroll
    for (int p = 0; p < 2; ++p)
#pragma unroll
        for (int nb = 0; nb < 4; ++nb) {
            int row = nb * 16 + cl;
            voffB[p][nb] = 8192 + ((row << 7) | (((quad * 2 + p) ^ (row & 7)) << 4));
        }

    auto stage = [&](int kt, int slot) {
        int key0 = kt << 6;
        unsigned short* Kd = smem + slot * 8192;   // 16KB per slot (in shorts)
        unsigned short* Vd = Kd + 4096;
#pragma unroll
        for (int i = 0; i < 2; ++i) {
            int s = t + 256 * i;
            int row = s >> 3, c16 = (s & 7) ^ (row & 7);
            gld_lds16(&Kbase[(size_t)(key0 + row) * HD + c16 * 8], &Kd[s * 8]);
            gld_lds16(&Vbase[(size_t)row * S_LEN + key0 + c16 * 8], &Vd[s * 8]);
        }
    };

    auto compute = [&](auto DIAGC, int slot, int key0) {
        constexpr bool DIAG = decltype(DIAGC)::v;
        const char* Kc = (const char*)(smem + slot * 8192);
        short8 aK0[4], aK1[4];
#pragma unroll
        for (int t4 = 0; t4 < 4; ++t4) {
            aK0[t4] = *(const short8*)(Kc + koff0[t4]);
            aK1[t4] = *(const short8*)(Kc + koff1[t4]);
        }
        U8 bv[2][4];
#pragma unroll
        for (int p = 0; p < 2; ++p)
#pragma unroll
            for (int nb = 0; nb < 4; ++nb)
                bv[p][nb].i = *(const int4_t*)(Kc + voffB[p][nb]);

#pragma unroll
        for (int qt = 0; qt < 2; ++qt) {
            unsigned int pk[4][2];
#pragma unroll
            for (int t4 = 0; t4 < 4; ++t4) {
                float4_t st = __builtin_amdgcn_mfma_f32_16x16x32_bf16(
                    aK1[t4], bQ[qt][1],
                    __builtin_amdgcn_mfma_f32_16x16x32_bf16(aK0[t4], bQ[qt][0], z, 0, 0, 0),
                    0, 0, 0);
                float e[4];
#pragma unroll
                for (int r = 0; r < 4; ++r) {
                    e[r] = __builtin_amdgcn_exp2f(st[r]);      // Q pre-scaled
                    if (DIAG) {
                        int key = key0 + t4 * 16 + quad * 4 + r;
                        e[r] = (key <= qb + qt * 16 + cl) ? e[r] : 0.f;
                    }
                }
                pk[t4][0] = cvtpk_bf16(e[0], e[1]);
                pk[t4][1] = cvtpk_bf16(e[2], e[3]);
            }
#pragma unroll
            for (int p = 0; p < 2; ++p) {
                U8 a; a.i = (int4_t){(int)pk[2 * p][0], (int)pk[2 * p][1],
                                     (int)pk[2 * p + 1][0], (int)pk[2 * p + 1][1]};
                accs[qt] = __builtin_amdgcn_mfma_f32_16x16x32_bf16(
                    a.s, onesf, accs[qt], 0, 0, 0);            // row-sum (denominator)
#pragma unroll
                for (int nb = 0; nb < 4; ++nb)
                    acc[qt][nb] = __builtin_amdgcn_mfma_f32_16x16x32_bf16(
                        a.s, bv[p][nb].s, acc[qt][nb], 0, 0, 0);
            }
        }
    };

    // --- counted-vmcnt 3-slot pipeline ---
    stage(0, 0);
    if (nkt_max > 1) stage(1, 1);          // nkt_max >= 17 always, but be safe
    int cb = 0, sb = 2;                    // compute slot, stage slot
    for (int u = 0; u < nkt_max; ++u) {
        if (u + 1 < nkt_max) {
            asm volatile("s_waitcnt vmcnt(4)" ::: "memory");  // own tile-u loads done
        } else {
            asm volatile("s_waitcnt vmcnt(0)" ::: "memory");  // final tile
        }
        __builtin_amdgcn_s_barrier();      // all waves' tile-u writes visible
        __builtin_amdgcn_sched_barrier(0);
        if (u + 2 < nkt_max) stage(u + 2, sb);   // slot vacated by compute(u-1)
        if (u < nkt) {
            if (u == nkt - 1) compute(BoolC<true>{},  cb, u << 6);
            else              compute(BoolC<false>{}, cb, u << 6);
        }
        cb = (cb == 2) ? 0 : cb + 1;
        sb = (sb == 2) ? 0 : sb + 1;
    }

    __syncthreads();   // full drain; all waves done with K/V LDS before stg aliasing
    unsigned short* stgw = smem + wave * 1088;   // 16 rows x 68 stride (2176B)

    // epilogue: normalize + coalesced store via per-wave LDS staging
#pragma unroll
    for (int qt = 0; qt < 2; ++qt) {
        float fr[4];
#pragma unroll
        for (int r = 0; r < 4; ++r) fr[r] = 1.f / accs[qt][r];
#pragma unroll
        for (int nb = 0; nb < 4; ++nb)
#pragma unroll
            for (int r = 0; r < 4; ++r) {
                unsigned int uu = __float_as_uint(acc[qt][nb][r] * fr[r]) + 0x8000u;
                stgw[(quad * 4 + r) * 68 + nb * 16 + cl] = (unsigned short)(uu >> 16);
            }
#pragma unroll
        for (int pass = 0; pass < 4; ++pass) {
            int idx = pass * 64 + lane;
            int row = idx >> 4, part = idx & 15;
            ushort4 v = *(const ushort4*)&stgw[row * 68 + part * 4];
            *(ushort4*)&AO[((size_t)b * S_LEN + qb + qt * 16 + row) * EMB + h * HD + part * 4] = v;
        }
    }
}

// ---------------------------------------------------------------------------
// GEMM2: out_f32 = AO[8192,1024]bf16 @ WoutT[1024,1024]^T + bout(f32)
// R10: __launch_bounds__(256, 3) (same reasoning as gemm_qkv).
// ---------------------------------------------------------------------------
__global__ __launch_bounds__(256, 3) void gemm_out(
    const unsigned short* __restrict__ A,
    const unsigned short* __restrict__ WT,
    const float* __restrict__ bias,
    float* __restrict__ out)
{
    __shared__ alignas(16) unsigned short smemA[3 * 4096];
    __shared__ alignas(16) unsigned short smemB[3 * 4096];
    const int K = 1024;
    const int NT = K / 32;
    int t = threadIdx.x;
    int wave = t >> 6, lane = t & 63, quad = lane >> 4, l = lane & 15;
    int bm = blockIdx.x * 128, bn = blockIdx.y * 128;
    int wm = (wave >> 1) * 64, wn = (wave & 1) * 64;
    int colrd = (quad ^ ((l >> 1) & 3)) * 8;

    float4_t z = {0.f, 0.f, 0.f, 0.f};
    float4_t acc[4][4];
#pragma unroll
    for (int i = 0; i < 4; ++i)
#pragma unroll
        for (int j = 0; j < 4; ++j) acc[i][j] = z;

    auto stage = [&](int kt, int slot) {
        int k0 = kt * 32;
        unsigned short* Ad = smemA + slot * 4096;
        unsigned short* Bd = smemB + slot * 4096;
#pragma unroll
        for (int it = 0; it < 2; ++it) {
            int c = t + 256 * it;
            int row = c >> 2;
            int col = ((c & 3) ^ ((c >> 3) & 3)) * 8;
            gld_lds16(&A [(size_t)(bm + row) * K + k0 + col], &Ad[c * 8]);
            gld_lds16(&WT[(size_t)(bn + row) * K + k0 + col], &Bd[c * 8]);
        }
    };

    auto compute = [&](int slot) {
        const unsigned short* Ac = smemA + slot * 4096;
        const unsigned short* Bc = smemB + slot * 4096;
        short8 af[4], bfr[4];
#pragma unroll
        for (int i = 0; i < 4; ++i)
            af[i] = *(const short8*)&Ac[(wm + i * 16 + l) * 32 + colrd];
#pragma unroll
        for (int j = 0; j < 4; ++j)
            bfr[j] = *(const short8*)&Bc[(wn + j * 16 + l) * 32 + colrd];
#pragma unroll
        for (int i = 0; i < 4; ++i)
#pragma unroll
            for (int j = 0; j < 4; ++j)
                acc[i][j] = __builtin_amdgcn_mfma_f32_16x16x32_bf16(
                    af[i], bfr[j], acc[i][j], 0, 0, 0);
    };

    stage(0, 0);
    stage(1, 1);
    int cs = 0, ss = 2;
    for (int u = 0; u < NT; ++u) {
        if (u + 1 < NT) {
            asm volatile("s_waitcnt vmcnt(4)" ::: "memory");
        } else {
            asm volatile("s_waitcnt vmcnt(0)" ::: "memory");
        }
        __builtin_amdgcn_s_barrier();
        __builtin_amdgcn_sched_barrier(0);
        if (u + 2 < NT) stage(u + 2, ss);
        compute(cs);
        cs = (cs == 2) ? 0 : cs + 1;
        ss = (ss == 2) ? 0 : ss + 1;
    }

#pragma unroll
    for (int j = 0; j < 4; ++j) {
        int gc = bn + wn + j * 16 + l;
        float bv = bias[gc];
#pragma unroll
        for (int i = 0; i < 4; ++i) {
#pragma unroll
            for (int r = 0; r < 4; ++r) {
                int gr = bm + wm + i * 16 + quad * 4 + r;
                out[(size_t)gr * EMB + gc] = acc[i][j][r] + bv;
            }
        }
    }
}

// ---------------------------------------------------------------------------
extern "C" void kernel_launch(void* const* d_in, const int* in_sizes, int n_in,
                              void* d_out, int out_size, void* d_ws, size_t ws_size,
                              hipStream_t stream) {
    const float* x    = (const float*)d_in[0];
    // d_in[1] = causal mask (int32 tril) -- implemented analytically, not read
    const float* Wqkv = (const float*)d_in[2];
    const float* bqkv = (const float*)d_in[3];
    const float* Wout = (const float*)d_in[4];
    const float* bout = (const float*)d_in[5];
    float* out = (float*)d_out;

    // workspace (bf16): Q 16MB | K 16MB | VT 16MB | Xb/AO 16MB (aliased) |
    // WqkvT 6MB | WoutT 2MB = 72MB
    char* ws = (char*)d_ws;
    const size_t SZ = (size_t)NB * NH * S_LEN * HD * 2;  // 16 MiB
    unsigned short* Qb    = (unsigned short*)(ws);
    unsigned short* Kb    = (unsigned short*)(ws + SZ);
    unsigned short* VTb   = (unsigned short*)(ws + 2 * SZ);
    unsigned short* Xb    = (unsigned short*)(ws + 3 * SZ);
    unsigned short* AO    = (unsigned short*)(ws + 3 * SZ);  // alias with Xb
    unsigned short* WqkvT = (unsigned short*)(ws + 4 * SZ);
    unsigned short* WoutT = (unsigned short*)(ws + 4 * SZ + (size_t)3 * EMB * EMB * 2);

    prep<<<dim3(20480), 256, 0, stream>>>(x, Xb, Wqkv, WqkvT, Wout, WoutT);
    gemm_qkv<<<dim3(MROWS / 128, 3 * EMB / 128), 256, 0, stream>>>(Xb, WqkvT, bqkv, Qb, Kb, VTb);
    flash_attn<<<dim3(1024), 256, 0, stream>>>(Qb, Kb, VTb, AO);
    gemm_out<<<dim3(MROWS / 128, EMB / 128), 256, 0, stream>>>(AO, WoutT, bout, out);
}

// Round 11
// 234.963 us; speedup vs baseline: 1.0335x; 1.0335x over previous
//
#include <hip/hip_runtime.h>

// Problem constants
#define S_LEN 2048
#define NH    16
#define HD    64
#define EMB   1024
#define NB    4
#define MROWS (NB * S_LEN)   // 8192

typedef __attribute__((ext_vector_type(8))) short  short8;   // 8 x bf16 bits (4 VGPRs)
typedef __attribute__((ext_vector_type(4))) float  float4_t; // MFMA C/D frag
typedef __attribute__((ext_vector_type(4))) int    int4_t;   // 16B int vector
union U8 { int4_t i; short8 s; };

__device__ __forceinline__ unsigned short f2bf(float f) {
    unsigned int x = __float_as_uint(f);
    unsigned int r = (x + 0x7fffu + ((x >> 16) & 1u)) >> 16;   // RNE
    return (unsigned short)r;
}

__device__ __forceinline__ unsigned int cvtpk_bf16(float lo, float hi) {
    unsigned int r;
    asm("v_cvt_pk_bf16_f32 %0, %1, %2" : "=v"(r) : "v"(lo), "v"(hi));
    return r;   // lo16 = bf16(lo), hi16 = bf16(hi), RNE
}

typedef const __attribute__((address_space(1))) unsigned int* gas_ptr;
typedef __attribute__((address_space(3))) unsigned int*       las_ptr;
__device__ __forceinline__ void gld_lds16(const void* g, void* l) {
    __builtin_amdgcn_global_load_lds((gas_ptr)g, (las_ptr)l, 16, 0, 0);
}

template<bool B> struct BoolC { static constexpr bool v = B; };

// Q pre-scale: 0.125 (1/sqrt(HD)) * log2(e) -> scores emerge in log2 domain
#define QSCALE 0.18033688011112042f

// ---------------------------------------------------------------------------
// prep: fused  (a) x f32->bf16 cvt, (b) Wqkv transpose, (c) Wout transpose.
// ---------------------------------------------------------------------------
__global__ __launch_bounds__(256) void prep(
    const float* __restrict__ x,    unsigned short* __restrict__ Xb,
    const float* __restrict__ Wqkv, unsigned short* __restrict__ WqkvT,
    const float* __restrict__ Wout, unsigned short* __restrict__ WoutT)
{
    __shared__ float tile[32][33];
    int bid = blockIdx.x, t = threadIdx.x;
    if (bid < 16384) {                       // cvt: 16384*256 = MROWS*EMB/2 exact
        int i = bid * 256 + t;
        float2 v = ((const float2*)x)[i];
        ushort2 o; o.x = f2bf(v.x); o.y = f2bf(v.y);
        ((ushort2*)Xb)[i] = o;
        return;
    }
    const float* in; unsigned short* out; int R, C, n0, r0;
    if (bid < 19456) {                       // Wqkv transpose: 96 x 32 tiles
        int b2 = bid - 16384;
        in = Wqkv; out = WqkvT; R = EMB; C = 3 * EMB;
        n0 = (b2 % 96) * 32; r0 = (b2 / 96) * 32;
    } else {                                 // Wout transpose: 32 x 32 tiles
        int b2 = bid - 19456;
        in = Wout; out = WoutT; R = EMB; C = EMB;
        n0 = (b2 & 31) * 32; r0 = (b2 >> 5) * 32;
    }
    int tx = t & 31, ty = t >> 5;
#pragma unroll
    for (int i = 0; i < 4; ++i)
        tile[ty + i * 8][tx] = in[(size_t)(r0 + ty + i * 8) * C + n0 + tx];
    __syncthreads();
#pragma unroll
    for (int i = 0; i < 4; ++i)
        out[(size_t)(n0 + ty + i * 8) * R + r0 + tx] = f2bf(tile[tx][ty + i * 8]);
}

// ---------------------------------------------------------------------------
// GEMM1: qkv = Xb[8192,1024] @ WqkvT[3072,1024]^T + bqkv(f32)
// ROUND 11: BK 32 -> 64.  Evidence: occupancy is pinned at ~2 blocks/CU
// regardless of LDS (R7: 16KB -> 28%; R9: 48KB -> 26%) and of launch
// bounds (R10 null), so the TLP lever is exhausted; and counted-vmcnt
// pipelining was NEUTRAL for this kernel (R7 72.5 vs R8 72.2 -- loads are
// L2-hot).  Residual vs the ~900TF structure ceiling is per-FLOP sync
// overhead: 32 iterations x {wait+barrier+issue} around only 16 MFMA.
// BK=64 halves sync events (16 iters, 32 MFMA between barriers).  LDS:
// 2 slots x 32KB = 64KB -- no occupancy to lose at 2 blocks/CU (m132's
// BK-upsize penalty doesn't apply).  Swizzle extends to 8 slots/row
// ((c&7)^(row&7)) -- the exact pattern verified clean in flash's K-buf
// (8 lanes/bank = ds_read_b128 minimum).  Plain vmcnt(0)+barrier per iter
// (loads get a full 32-MFMA iteration to land).  (256,2): BK=64 live set
// ~100 VGPR; a (256,3) 85-cap would spill (R5 lesson).
// Epilogue unchanged from R9 (coalesced LDS-staged; conflicts 6.3M->393K).
// ---------------------------------------------------------------------------
__global__ __launch_bounds__(256, 2) void gemm_qkv(
    const unsigned short* __restrict__ X,
    const unsigned short* __restrict__ WT,
    const float* __restrict__ bias,
    unsigned short* __restrict__ Qb,
    unsigned short* __restrict__ Kb,
    unsigned short* __restrict__ VTb)
{
    // 64KB: A slots [0,16384), B slots [16384,32768) (shorts).
    // Epilogue staging reuses [0,16896) after a full __syncthreads.
    __shared__ alignas(16) unsigned short smem[32768];
    const int K = 1024;
    const int NT = K / 64;                 // 16 K-tiles
    int t = threadIdx.x;
    int wave = t >> 6, lane = t & 63, quad = lane >> 4, l = lane & 15;
    int bm = blockIdx.x * 128, bn = blockIdx.y * 128;
    int wm = (wave >> 1) * 64, wn = (wave & 1) * 64;

    float4_t z = {0.f, 0.f, 0.f, 0.f};
    float4_t acc[4][4];
#pragma unroll
    for (int i = 0; i < 4; ++i)
#pragma unroll
        for (int j = 0; j < 4; ++j) acc[i][j] = z;

    auto stage = [&](int kt, int slot) {
        int k0 = kt * 64;
        unsigned short* Ad = smem + slot * 8192;
        unsigned short* Bd = smem + 16384 + slot * 8192;
#pragma unroll
        for (int it = 0; it < 4; ++it) {
            int c = t + 256 * it;                    // 0..1023 16B-chunks
            int row = c >> 3;                        // 8 chunks per 128B row
            int col = ((c & 7) ^ (row & 7)) * 8;     // source pre-swizzle
            gld_lds16(&X [(size_t)(bm + row) * K + k0 + col], &Ad[c * 8]);
            gld_lds16(&WT[(size_t)(bn + row) * K + k0 + col], &Bd[c * 8]);
        }
    };

    auto compute = [&](int slot) {
        const unsigned short* Ac = smem + slot * 8192;
        const unsigned short* Bc = smem + 16384 + slot * 8192;
#pragma unroll
        for (int kk = 0; kk < 2; ++kk) {
            int srd = ((kk * 4 + quad) ^ (l & 7)) * 8;   // swizzled 16B slot
            short8 af[4], bfr[4];
#pragma unroll
            for (int i = 0; i < 4; ++i)
                af[i] = *(const short8*)&Ac[(wm + i * 16 + l) * 64 + srd];
#pragma unroll
            for (int j = 0; j < 4; ++j)
                bfr[j] = *(const short8*)&Bc[(wn + j * 16 + l) * 64 + srd];
#pragma unroll
            for (int i = 0; i < 4; ++i)
#pragma unroll
                for (int j = 0; j < 4; ++j)
                    acc[i][j] = __builtin_amdgcn_mfma_f32_16x16x32_bf16(
                        af[i], bfr[j], acc[i][j], 0, 0, 0);
        }
    };

    stage(0, 0);
    for (int u = 0; u < NT; ++u) {
        asm volatile("s_waitcnt vmcnt(0)" ::: "memory");   // tile-u loads landed
        __builtin_amdgcn_s_barrier();                      // writes visible to all
        __builtin_amdgcn_sched_barrier(0);
        if (u + 1 < NT) stage(u + 1, (u + 1) & 1);         // fly under 32 MFMA
        compute(u & 1);
    }

    // ---- LDS-staged coalesced epilogue ----
    __syncthreads();                       // all waves done reading K-loop LDS
    int which = bn >> 10;                  // block-uniform (bn mult of 128)
    int bnr = bn & 1023;
    int b = bm >> 11;
    if (which == 2) {
        // V: stage transposed [c][pi-slot(s)] (stride 132 shorts)
#pragma unroll
        for (int j = 0; j < 4; ++j) {
            float bv = bias[bn + wn + j * 16 + l];
            int c = wn + j * 16 + l;
#pragma unroll
            for (int i = 0; i < 4; ++i) {
                uint2 vv;
                vv.x = cvtpk_bf16(acc[i][j][0] + bv, acc[i][j][1] + bv);
                vv.y = cvtpk_bf16(acc[i][j][2] + bv, acc[i][j][3] + bv);
                // pi([i|quad|r]) = quad*16 + i*4 + r, within the wm 64-group
                *(uint2*)&smem[c * 132 + wm + quad * 16 + i * 4] = vv;
            }
        }
        __syncthreads();
        int sbase = bm & 2047;
#pragma unroll
        for (int pass = 0; pass < 8; ++pass) {
            int c = pass * 16 + (t >> 4);
            int sp = (t & 15) * 8;
            int rem = bnr + c, h = rem >> 6, d = rem & 63;
            uint2 lo = *(const uint2*)&smem[c * 132 + sp];
            uint2 hi = *(const uint2*)&smem[c * 132 + sp + 4];
            int4_t v = {(int)lo.x, (int)lo.y, (int)hi.x, (int)hi.y};
            *(int4_t*)&VTb[((size_t)(b * NH + h) * HD + d) * S_LEN + sbase + sp] = v;
        }
    } else {
        // Q/K: stage [s][c] (stride 132 shorts)
#pragma unroll
        for (int j = 0; j < 4; ++j) {
            float bv = bias[bn + wn + j * 16 + l];
            int c = wn + j * 16 + l;
#pragma unroll
            for (int i = 0; i < 4; ++i)
#pragma unroll
                for (int r = 0; r < 4; ++r) {
                    float ov = acc[i][j][r] + bv;
                    if (which == 0) ov *= QSCALE;
                    smem[(wm + i * 16 + quad * 4 + r) * 132 + c] = f2bf(ov);
                }
        }
        __syncthreads();
        unsigned short* dst = which ? Kb : Qb;
        int s0g = bm & 2047;
#pragma unroll
        for (int pass = 0; pass < 8; ++pass) {
            int s = pass * 16 + (t >> 4);
            int cp = (t & 15) * 8;
            int rem = bnr + cp, h = rem >> 6, d = rem & 63;
            uint2 lo = *(const uint2*)&smem[s * 132 + cp];
            uint2 hi = *(const uint2*)&smem[s * 132 + cp + 4];
            int4_t v = {(int)lo.x, (int)lo.y, (int)hi.x, (int)hi.y};
            *(int4_t*)&dst[((size_t)(b * NH + h) * S_LEN + s0g + s) * HD + d] = v;
        }
    }
}

// ---------------------------------------------------------------------------
// Flash attention (causal), LDS-staged K/V shared across the block.
// (Unchanged: counted-vmcnt 3-slot pipeline, balanced chunks, permuted-V
// single-b128 PV reads, MFMA row-sum denominator, (256,2).)
// ---------------------------------------------------------------------------
__global__ __launch_bounds__(256, 2) void flash_attn(
    const unsigned short* __restrict__ Qb,
    const unsigned short* __restrict__ Kb,
    const unsigned short* __restrict__ VTb,
    unsigned short* __restrict__ AO)
{
    // 3 buffers x (K 8KB | V 8KB) = 48KB; epilogue reuses first 8704B as
    // per-wave O staging (after full __syncthreads).
    __shared__ alignas(16) unsigned short smem[24576];

    int t = threadIdx.x, wave = t >> 6, lane = t & 63, quad = lane >> 4, cl = lane & 15;
    int blk = blockIdx.x;                        // 0..1023
    int bh = (blk & 7) + 8 * ((blk >> 3) & 7);   // XCD-pinned heads
    int g = blk >> 6;                            // 0..15
    int b = bh >> 4, h = bh & 15;
    int ci = (wave & 2) ? (62 - 2 * g + (wave & 1)) : (2 * g + (wave & 1));
    int qb = 32 * ci;
    int nkt = (ci >> 1) + 1;                     // tiles this wave computes
    int nkt_max = 32 - g;                        // tiles the block stages (>=17)

    const unsigned short* Qbase = Qb  + (size_t)bh * S_LEN * HD;
    const unsigned short* Kbase = Kb  + (size_t)bh * S_LEN * HD;
    const unsigned short* Vbase = VTb + (size_t)bh * HD * S_LEN;

    float4_t z = {0.f, 0.f, 0.f, 0.f};
    short8 onesf;
#pragma unroll
    for (int i = 0; i < 8; ++i) onesf[i] = (short)0x3F80;   // bf16 1.0

    short8 bQ[2][2];
#pragma unroll
    for (int qt = 0; qt < 2; ++qt)
#pragma unroll
        for (int hh = 0; hh < 2; ++hh)
            bQ[qt][hh] = *(const short8*)&Qbase[(size_t)(qb + qt * 16 + cl) * HD + hh * 32 + quad * 8];

    float4_t acc[2][4], accs[2];
#pragma unroll
    for (int qt = 0; qt < 2; ++qt) {
        accs[qt] = z;
#pragma unroll
        for (int nb = 0; nb < 4; ++nb) acc[qt][nb] = z;
    }

    // kt-invariant swizzled LDS read offsets (bytes, relative to buffer base)
    int koff0[4], koff1[4];
#pragma unroll
    for (int t4 = 0; t4 < 4; ++t4) {
        int row = t4 * 16 + cl, sw = row & 7;
        koff0[t4] = (row << 7) | ((quad ^ sw) << 4);
        koff1[t4] = (row << 7) | (((quad + 4) ^ sw) << 4);
    }
    // V (permuted layout): B-frag for (p,quad) at 16B slot (quad*2+p)^(row&7)
    int voffB[2][4];
#pragma unroll
    for (int p = 0; p < 2; ++p)
#pragma unroll
        for (int nb = 0; nb < 4; ++nb) {
            int row = nb * 16 + cl;
            voffB[p][nb] = 8192 + ((row << 7) | (((quad * 2 + p) ^ (row & 7)) << 4));
        }

    auto stage = [&](int kt, int slot) {
        int key0 = kt << 6;
        unsigned short* Kd = smem + slot * 8192;   // 16KB per slot (in shorts)
        unsigned short* Vd = Kd + 4096;
#pragma unroll
        for (int i = 0; i < 2; ++i) {
            int s = t + 256 * i;
            int row = s >> 3, c16 = (s & 7) ^ (row & 7);
            gld_lds16(&Kbase[(size_t)(key0 + row) * HD + c16 * 8], &Kd[s * 8]);
            gld_lds16(&Vbase[(size_t)row * S_LEN + key0 + c16 * 8], &Vd[s * 8]);
        }
    };

    auto compute = [&](auto DIAGC, int slot, int key0) {
        constexpr bool DIAG = decltype(DIAGC)::v;
        const char* Kc = (const char*)(smem + slot * 8192);
        short8 aK0[4], aK1[4];
#pragma unroll
        for (int t4 = 0; t4 < 4; ++t4) {
            aK0[t4] = *(const short8*)(Kc + koff0[t4]);
            aK1[t4] = *(const short8*)(Kc + koff1[t4]);
        }
        U8 bv[2][4];
#pragma unroll
        for (int p = 0; p < 2; ++p)
#pragma unroll
            for (int nb = 0; nb < 4; ++nb)
                bv[p][nb].i = *(const int4_t*)(Kc + voffB[p][nb]);

#pragma unroll
        for (int qt = 0; qt < 2; ++qt) {
            unsigned int pk[4][2];
#pragma unroll
            for (int t4 = 0; t4 < 4; ++t4) {
                float4_t st = __builtin_amdgcn_mfma_f32_16x16x32_bf16(
                    aK1[t4], bQ[qt][1],
                    __builtin_amdgcn_mfma_f32_16x16x32_bf16(aK0[t4], bQ[qt][0], z, 0, 0, 0),
                    0, 0, 0);
                float e[4];
#pragma unroll
                for (int r = 0; r < 4; ++r) {
                    e[r] = __builtin_amdgcn_exp2f(st[r]);      // Q pre-scaled
                    if (DIAG) {
                        int key = key0 + t4 * 16 + quad * 4 + r;
                        e[r] = (key <= qb + qt * 16 + cl) ? e[r] : 0.f;
                    }
                }
                pk[t4][0] = cvtpk_bf16(e[0], e[1]);
                pk[t4][1] = cvtpk_bf16(e[2], e[3]);
            }
#pragma unroll
            for (int p = 0; p < 2; ++p) {
                U8 a; a.i = (int4_t){(int)pk[2 * p][0], (int)pk[2 * p][1],
                                     (int)pk[2 * p + 1][0], (int)pk[2 * p + 1][1]};
                accs[qt] = __builtin_amdgcn_mfma_f32_16x16x32_bf16(
                    a.s, onesf, accs[qt], 0, 0, 0);            // row-sum (denominator)
#pragma unroll
                for (int nb = 0; nb < 4; ++nb)
                    acc[qt][nb] = __builtin_amdgcn_mfma_f32_16x16x32_bf16(
                        a.s, bv[p][nb].s, acc[qt][nb], 0, 0, 0);
            }
        }
    };

    // --- counted-vmcnt 3-slot pipeline ---
    stage(0, 0);
    if (nkt_max > 1) stage(1, 1);          // nkt_max >= 17 always, but be safe
    int cb = 0, sb = 2;                    // compute slot, stage slot
    for (int u = 0; u < nkt_max; ++u) {
        if (u + 1 < nkt_max) {
            asm volatile("s_waitcnt vmcnt(4)" ::: "memory");  // own tile-u loads done
        } else {
            asm volatile("s_waitcnt vmcnt(0)" ::: "memory");  // final tile
        }
        __builtin_amdgcn_s_barrier();      // all waves' tile-u writes visible
        __builtin_amdgcn_sched_barrier(0);
        if (u + 2 < nkt_max) stage(u + 2, sb);   // slot vacated by compute(u-1)
        if (u < nkt) {
            if (u == nkt - 1) compute(BoolC<true>{},  cb, u << 6);
            else              compute(BoolC<false>{}, cb, u << 6);
        }
        cb = (cb == 2) ? 0 : cb + 1;
        sb = (sb == 2) ? 0 : sb + 1;
    }

    __syncthreads();   // full drain; all waves done with K/V LDS before stg aliasing
    unsigned short* stgw = smem + wave * 1088;   // 16 rows x 68 stride (2176B)

    // epilogue: normalize + coalesced store via per-wave LDS staging
#pragma unroll
    for (int qt = 0; qt < 2; ++qt) {
        float fr[4];
#pragma unroll
        for (int r = 0; r < 4; ++r) fr[r] = 1.f / accs[qt][r];
#pragma unroll
        for (int nb = 0; nb < 4; ++nb)
#pragma unroll
            for (int r = 0; r < 4; ++r) {
                unsigned int uu = __float_as_uint(acc[qt][nb][r] * fr[r]) + 0x8000u;
                stgw[(quad * 4 + r) * 68 + nb * 16 + cl] = (unsigned short)(uu >> 16);
            }
#pragma unroll
        for (int pass = 0; pass < 4; ++pass) {
            int idx = pass * 64 + lane;
            int row = idx >> 4, part = idx & 15;
            ushort4 v = *(const ushort4*)&stgw[row * 68 + part * 4];
            *(ushort4*)&AO[((size_t)b * S_LEN + qb + qt * 16 + row) * EMB + h * HD + part * 4] = v;
        }
    }
}

// ---------------------------------------------------------------------------
// GEMM2: out_f32 = AO[8192,1024]bf16 @ WoutT[1024,1024]^T + bout(f32)
// R11: same BK=64 upgrade as gemm_qkv.
// ---------------------------------------------------------------------------
__global__ __launch_bounds__(256, 2) void gemm_out(
    const unsigned short* __restrict__ A,
    const unsigned short* __restrict__ WT,
    const float* __restrict__ bias,
    float* __restrict__ out)
{
    __shared__ alignas(16) unsigned short smem[32768];
    const int K = 1024;
    const int NT = K / 64;
    int t = threadIdx.x;
    int wave = t >> 6, lane = t & 63, quad = lane >> 4, l = lane & 15;
    int bm = blockIdx.x * 128, bn = blockIdx.y * 128;
    int wm = (wave >> 1) * 64, wn = (wave & 1) * 64;

    float4_t z = {0.f, 0.f, 0.f, 0.f};
    float4_t acc[4][4];
#pragma unroll
    for (int i = 0; i < 4; ++i)
#pragma unroll
        for (int j = 0; j < 4; ++j) acc[i][j] = z;

    auto stage = [&](int kt, int slot) {
        int k0 = kt * 64;
        unsigned short* Ad = smem + slot * 8192;
        unsigned short* Bd = smem + 16384 + slot * 8192;
#pragma unroll
        for (int it = 0; it < 4; ++it) {
            int c = t + 256 * it;
            int row = c >> 3;
            int col = ((c & 7) ^ (row & 7)) * 8;
            gld_lds16(&A [(size_t)(bm + row) * K + k0 + col], &Ad[c * 8]);
            gld_lds16(&WT[(size_t)(bn + row) * K + k0 + col], &Bd[c * 8]);
        }
    };

    auto compute = [&](int slot) {
        const unsigned short* Ac = smem + slot * 8192;
        const unsigned short* Bc = smem + 16384 + slot * 8192;
#pragma unroll
        for (int kk = 0; kk < 2; ++kk) {
            int srd = ((kk * 4 + quad) ^ (l & 7)) * 8;
            short8 af[4], bfr[4];
#pragma unroll
            for (int i = 0; i < 4; ++i)
                af[i] = *(const short8*)&Ac[(wm + i * 16 + l) * 64 + srd];
#pragma unroll
            for (int j = 0; j < 4; ++j)
                bfr[j] = *(const short8*)&Bc[(wn + j * 16 + l) * 64 + srd];
#pragma unroll
            for (int i = 0; i < 4; ++i)
#pragma unroll
                for (int j = 0; j < 4; ++j)
                    acc[i][j] = __builtin_amdgcn_mfma_f32_16x16x32_bf16(
                        af[i], bfr[j], acc[i][j], 0, 0, 0);
        }
    };

    stage(0, 0);
    for (int u = 0; u < NT; ++u) {
        asm volatile("s_waitcnt vmcnt(0)" ::: "memory");
        __builtin_amdgcn_s_barrier();
        __builtin_amdgcn_sched_barrier(0);
        if (u + 1 < NT) stage(u + 1, (u + 1) & 1);
        compute(u & 1);
    }

#pragma unroll
    for (int j = 0; j < 4; ++j) {
        int gc = bn + wn + j * 16 + l;
        float bv = bias[gc];
#pragma unroll
        for (int i = 0; i < 4; ++i) {
#pragma unroll
            for (int r = 0; r < 4; ++r) {
                int gr = bm + wm + i * 16 + quad * 4 + r;
                out[(size_t)gr * EMB + gc] = acc[i][j][r] + bv;
            }
        }
    }
}

// ---------------------------------------------------------------------------
extern "C" void kernel_launch(void* const* d_in, const int* in_sizes, int n_in,
                              void* d_out, int out_size, void* d_ws, size_t ws_size,
                              hipStream_t stream) {
    const float* x    = (const float*)d_in[0];
    // d_in[1] = causal mask (int32 tril) -- implemented analytically, not read
    const float* Wqkv = (const float*)d_in[2];
    const float* bqkv = (const float*)d_in[3];
    const float* Wout = (const float*)d_in[4];
    const float* bout = (const float*)d_in[5];
    float* out = (float*)d_out;

    // workspace (bf16): Q 16MB | K 16MB | VT 16MB | Xb/AO 16MB (aliased) |
    // WqkvT 6MB | WoutT 2MB = 72MB
    char* ws = (char*)d_ws;
    const size_t SZ = (size_t)NB * NH * S_LEN * HD * 2;  // 16 MiB
    unsigned short* Qb    = (unsigned short*)(ws);
    unsigned short* Kb    = (unsigned short*)(ws + SZ);
    unsigned short* VTb   = (unsigned short*)(ws + 2 * SZ);
    unsigned short* Xb    = (unsigned short*)(ws + 3 * SZ);
    unsigned short* AO    = (unsigned short*)(ws + 3 * SZ);  // alias with Xb
    unsigned short* WqkvT = (unsigned short*)(ws + 4 * SZ);
    unsigned short* WoutT = (unsigned short*)(ws + 4 * SZ + (size_t)3 * EMB * EMB * 2);

    prep<<<dim3(20480), 256, 0, stream>>>(x, Xb, Wqkv, WqkvT, Wout, WoutT);
    gemm_qkv<<<dim3(MROWS / 128, 3 * EMB / 128), 256, 0, stream>>>(Xb, WqkvT, bqkv, Qb, Kb, VTb);
    flash_attn<<<dim3(1024), 256, 0, stream>>>(Qb, Kb, VTb, AO);
    gemm_out<<<dim3(MROWS / 128, EMB / 128), 256, 0, stream>>>(AO, WoutT, bout, out);
}